// Round 11
// baseline (80.278 us; speedup 1.0000x reference)
//
#include <hip/hip_runtime.h>
#include <math.h>

#define HH 128
#define BB 2
#define FF 1024
#define CC 16
#define PIF 3.14159265358979323846f

// ---------------------------------------------------------------------------
// Kernel 1: per-face setup (once, 2048 threads total).
// f32 record (16 floats, 64B):
//   [0..8]  A0 B0 C0 A1 B1 C1 A2 B2 C2   (l_i = A*py + B*px + C, 1/area folded)
//   [9..11] ZA ZB ZC                     (zt = clamp(ZA*py+ZB*px+ZC, 0, 1))
//   [12]    sg   [13] eps (f32 sign-uncertainty band)   [14..15] pad
// f64 record (10 doubles): exact A..C. Used only when min|l_f32| < eps; the
// f64 signs reproduce the exact decisions (R3..R9: absmax 0.008-0.016 vs
// threshold 0.565 -- no boundary-flip lottery).
// ---------------------------------------------------------------------------
__global__ __launch_bounds__(256) void fof_setup(const float* __restrict__ v,
                                                 float* __restrict__ recf,
                                                 double* __restrict__ recd,
                                                 int* __restrict__ bbox) {
    int idx = blockIdx.x * 256 + threadIdx.x;
    if (idx >= BB * FF) return;
    const float* vp = v + (size_t)idx * 9;

    double X0 = fma((double)vp[0],  64.0, 63.5);
    double Y0 = fma((double)vp[1], -64.0, 63.5);
    double Z0 = (double)vp[2];
    double X1 = fma((double)vp[3],  64.0, 63.5);
    double Y1 = fma((double)vp[4], -64.0, 63.5);
    double Z1 = (double)vp[5];
    double X2 = fma((double)vp[6],  64.0, 63.5);
    double Y2 = fma((double)vp[7], -64.0, 63.5);
    double Z2 = (double)vp[8];

    double d0x = X2 - X1, d0y = Y2 - Y1;
    double d1x = X0 - X2, d1y = Y0 - Y2;
    double d2x = X1 - X0, d2y = Y1 - Y0;
    double area = d1x * d2y - d1y * d2x;
    double inv  = (area != 0.0) ? 1.0 / area : 0.0;
    double sg   = (area > 0.0) ? 1.0 : ((area < 0.0) ? -1.0 : 0.0);

    double A0 = d0x * inv, B0 = -d0y * inv, C0 = (d0y * X1 - d0x * Y1) * inv;
    double A1 = d1x * inv, B1 = -d1y * inv, C1 = (d1y * X2 - d1x * Y2) * inv;
    double A2 = d2x * inv, B2 = -d2y * inv, C2 = (d2y * X0 - d2x * Y0) * inv;

    double ZA = (A0 * Z0 + A1 * Z1 + A2 * Z2) * 0.5;
    double ZB = (B0 * Z0 + B1 * Z1 + B2 * Z2) * 0.5;
    double ZC = (C0 * Z0 + C1 * Z1 + C2 * Z2 + 1.0) * 0.5;

    // f32 sign-uncertainty band (f64->f32 conversion + 2-fma eval rounding)
    double M0 = (fabs(A0) + fabs(B0)) * 135.0 + fabs(C0);
    double M1 = (fabs(A1) + fabs(B1)) * 135.0 + fabs(C1);
    double M2 = (fabs(A2) + fabs(B2)) * 135.0 + fabs(C2);
    float eps = (float)(1e-6 * fmax(M0, fmax(M1, M2)));

    float* rf = recf + (size_t)idx * 16;
    rf[0] = (float)A0; rf[1] = (float)B0; rf[2] = (float)C0;
    rf[3] = (float)A1; rf[4] = (float)B1; rf[5] = (float)C1;
    rf[6] = (float)A2; rf[7] = (float)B2; rf[8] = (float)C2;
    rf[9] = (float)ZA; rf[10] = (float)ZB; rf[11] = (float)ZC;
    rf[12] = (float)sg; rf[13] = eps; rf[14] = 0.f; rf[15] = 0.f;

    double* rd = recd + (size_t)idx * 10;
    rd[0] = A0; rd[1] = B0; rd[2] = C0;
    rd[3] = A1; rd[4] = B1; rd[5] = C1;
    rd[6] = A2; rd[7] = B2; rd[8] = C2; rd[9] = 0.0;

    float x0 = (float)X0, y0 = (float)Y0;
    float x1 = (float)X1, y1 = (float)Y1;
    float x2 = (float)X2, y2 = (float)Y2;
    float xmn = fminf(x0, fminf(x1, x2)) - 0.5f;
    float xmx = fmaxf(x0, fmaxf(x1, x2)) + 0.5f;
    float ymn = fminf(y0, fminf(y1, y2)) - 0.5f;
    float ymx = fmaxf(y0, fmaxf(y1, y2)) + 0.5f;
    int txmin = (int)ceilf((xmn - 7.f) * 0.125f);
    int txmax = (int)floorf(xmx * 0.125f);
    int tymin = (int)ceilf((ymn - 7.f) * 0.125f);
    int tymax = (int)floorf(ymx * 0.125f);
    txmin = max(0, min(15, txmin)); txmax = max(0, min(15, txmax));
    tymin = max(0, min(15, tymin)); tymax = max(0, min(15, tymax));
    bbox[idx] = (sg == 0.0) ? (1 | (0 << 8) | (1 << 16) | (0 << 24))
                            : (txmin | (txmax << 8) | (tymin << 16) | (tymax << 24));
}

// ---------------------------------------------------------------------------
// Kernel 2: main. 512 blocks (b,tile with XOR-0x88 load-balance pairing,
// proven R7) x 1024 threads; 16 waves x 64 faces -> block writes FINAL
// scaled output. R10 change: harmonic evaluation by DIRECT hardware sine.
// v_sin_f32 takes revolutions with HW range reduction, so
//   sin(k*pi*zt) = v_sin(k * zt/2),  k = 1..15, arg <= 7.5 rev.
// 16 INDEPENDENT trans ops replace the 7-deep sequential Chebyshev pk-FMA
// chain -> per-iteration serial latency ~180 -> ~40 cyc. (R6-R9 evidence:
// fof_main pinned at 21-24 us across 4 structural variants => bound by the
// per-iteration dependency chain, not balance or s_load latency.)
// ---------------------------------------------------------------------------
__global__ __launch_bounds__(1024) void fof_main(const float* __restrict__ recf,
                                                 const double* __restrict__ recd,
                                                 const int* __restrict__ bbox,
                                                 float* __restrict__ out) {
    __shared__ float S1[8][64][17];
    __shared__ float S2[4][64][17];
    __shared__ float S3[2][64][17];
    __shared__ float S4[64][17];

    int blk  = blockIdx.x;                 // 0..511
    int b    = blk & 1;
    int t0   = blk >> 1;                   // 0..255
    int tile = b ? (t0 ^ 0x88) : t0;       // heavy<->light pairing
    int ty   = tile >> 4;
    int tx   = tile & 15;
    int wv   = __builtin_amdgcn_readfirstlane((int)(threadIdx.x >> 6));  // 0..15
    int lane = threadIdx.x & 63;

    float px = (float)(tx * 8 + (lane & 7));
    float py = (float)(ty * 8 + (lane >> 3));

    float accv[CC];
#pragma unroll
    for (int k = 0; k < CC; ++k) accv[k] = 0.f;

    int gfb = b * FF + wv * 64;            // this wave's 64-face chunk

    int pk = bbox[gfb + lane];
    int txmin = pk & 255, txmax = (pk >> 8) & 255;
    int tymin = (pk >> 16) & 255, tymax = (pk >> 24) & 255;
    bool pass = !((tx < txmin) | (tx > txmax) | (ty < tymin) | (ty > tymax));
    unsigned long long m = __ballot(pass);

    while (m) {
        int j = __builtin_amdgcn_readfirstlane(__builtin_ctzll(m));
        m &= m - 1;
        const float* r = recf + (size_t)(gfb + j) * 16;  // wave-uniform s_load

        float l0 = fmaf(r[0], py, fmaf(r[1], px, r[2]));
        float l1 = fmaf(r[3], py, fmaf(r[4], px, r[5]));
        float l2 = fmaf(r[6], py, fmaf(r[7], px, r[8]));
        float lmin = fminf(fminf(l0, l1), l2);
        float amin = fminf(fminf(__builtin_fabsf(l0), __builtin_fabsf(l1)),
                           __builtin_fabsf(l2));
        bool inside = lmin >= 0.f;
        if (__builtin_expect(__any(amin < r[13]), 0)) {  // rare exact path
            const double* rd = recd + (size_t)(gfb + j) * 10;
            double pyd = (double)py, pxd = (double)px;
            double L0 = fma(rd[0], pyd, fma(rd[1], pxd, rd[2]));
            double L1 = fma(rd[3], pyd, fma(rd[4], pxd, rd[5]));
            double L2 = fma(rd[6], pyd, fma(rd[7], pxd, rd[8]));
            inside = (L0 >= 0.0) & (L1 >= 0.0) & (L2 >= 0.0);
        }
        float w = inside ? r[12] : 0.f;

        if (__any(w != 0.f)) {
            float zt = fmaf(r[9], py, fmaf(r[10], px, r[11]));
            zt = fminf(fmaxf(zt, 0.f), 1.f);
            float hz = 0.5f * zt;              // revolutions for k=1
            accv[0] = fmaf(w, 1.f - zt, accv[0]);
#pragma unroll
            for (int k = 1; k < CC; ++k) {
                float arg = hz * (float)k;     // k*zt/2 rev == k*pi*zt rad
                float sk;
                asm("v_sin_f32 %0, %1" : "=v"(sk) : "v"(arg));
                accv[k] = fmaf(w, sk, accv[k]);
            }
        }
    }

    // 16 -> 8 -> 4 -> 2 -> 1 (disjoint stage buffers; write-sync-read)
    if (wv >= 8) {
#pragma unroll
        for (int k = 0; k < CC; ++k) S1[wv - 8][lane][k] = accv[k];
    }
    __syncthreads();
    if (wv < 8) {
#pragma unroll
        for (int k = 0; k < CC; ++k) accv[k] += S1[wv][lane][k];
    }
    if (wv >= 4 && wv < 8) {
#pragma unroll
        for (int k = 0; k < CC; ++k) S2[wv - 4][lane][k] = accv[k];
    }
    __syncthreads();
    if (wv < 4) {
#pragma unroll
        for (int k = 0; k < CC; ++k) accv[k] += S2[wv][lane][k];
    }
    if (wv == 2 || wv == 3) {
#pragma unroll
        for (int k = 0; k < CC; ++k) S3[wv - 2][lane][k] = accv[k];
    }
    __syncthreads();
    if (wv < 2) {
#pragma unroll
        for (int k = 0; k < CC; ++k) accv[k] += S3[wv][lane][k];
    }
    if (wv == 1) {
#pragma unroll
        for (int k = 0; k < CC; ++k) S4[lane][k] = accv[k];
    }
    __syncthreads();
    if (wv == 0) {
        int xo = tx * 8 + (lane & 7);
        int yo = ty * 8 + (lane >> 3);
#pragma unroll
        for (int k = 0; k < CC; ++k) {
            float val = accv[k] + S4[lane][k];
            float scale = (k == 0) ? 1.f : (-2.f / (PIF * (float)k));
            out[(((b * CC + k) * HH) + yo) * HH + xo] = val * scale;
        }
    }
}

extern "C" void kernel_launch(void* const* d_in, const int* in_sizes, int n_in,
                              void* d_out, int out_size, void* d_ws, size_t ws_size,
                              hipStream_t stream) {
    const float* v = (const float*)d_in[0];
    float* out = (float*)d_out;

    // ws: recf 2048*16*4 = 131072 B | recd 2048*10*8 = 163840 B | bbox 8192 B
    float*  recf = (float*)d_ws;
    double* recd = (double*)((char*)d_ws + 131072);
    int*    bbox = (int*)((char*)d_ws + 131072 + 163840);

    fof_setup<<<(BB * FF + 255) / 256, 256, 0, stream>>>(v, recf, recd, bbox);
    fof_main<<<BB * 256, 1024, 0, stream>>>(recf, recd, bbox, out);
}

// Round 12
// 74.328 us; speedup vs baseline: 1.0801x; 1.0801x over previous
//
#include <hip/hip_runtime.h>
#include <math.h>

#define HH 128
#define BB 2
#define FF 1024
#define CC 16
#define PIF 3.14159265358979323846f

typedef float f2 __attribute__((ext_vector_type(2)));

// ---------------------------------------------------------------------------
// Kernel 1: per-face setup (once, 2048 threads total).
// f32 record (16 floats, 64B):
//   [0..8]  A0 B0 C0 A1 B1 C1 A2 B2 C2   (l_i = A*py + B*px + C, 1/area folded)
//   [9..11] ZA ZB ZC                     (zt = clamp(ZA*py+ZB*px+ZC, 0, 1))
//   [12]    sg   [13] eps (f32 sign-uncertainty band)   [14..15] pad
// f64 record (10 doubles): exact A..C, used when min|l_f32| < eps (rare).
// R3..R11 evidence: f64-certified decisions -> absmax 0.008-0.016, no lottery.
// ---------------------------------------------------------------------------
__global__ __launch_bounds__(256) void fof_setup(const float* __restrict__ v,
                                                 float* __restrict__ recf,
                                                 double* __restrict__ recd,
                                                 int* __restrict__ bbox) {
    int idx = blockIdx.x * 256 + threadIdx.x;
    if (idx >= BB * FF) return;
    const float* vp = v + (size_t)idx * 9;

    double X0 = fma((double)vp[0],  64.0, 63.5);
    double Y0 = fma((double)vp[1], -64.0, 63.5);
    double Z0 = (double)vp[2];
    double X1 = fma((double)vp[3],  64.0, 63.5);
    double Y1 = fma((double)vp[4], -64.0, 63.5);
    double Z1 = (double)vp[5];
    double X2 = fma((double)vp[6],  64.0, 63.5);
    double Y2 = fma((double)vp[7], -64.0, 63.5);
    double Z2 = (double)vp[8];

    double d0x = X2 - X1, d0y = Y2 - Y1;
    double d1x = X0 - X2, d1y = Y0 - Y2;
    double d2x = X1 - X0, d2y = Y1 - Y0;
    double area = d1x * d2y - d1y * d2x;
    double inv  = (area != 0.0) ? 1.0 / area : 0.0;
    double sg   = (area > 0.0) ? 1.0 : ((area < 0.0) ? -1.0 : 0.0);

    double A0 = d0x * inv, B0 = -d0y * inv, C0 = (d0y * X1 - d0x * Y1) * inv;
    double A1 = d1x * inv, B1 = -d1y * inv, C1 = (d1y * X2 - d1x * Y2) * inv;
    double A2 = d2x * inv, B2 = -d2y * inv, C2 = (d2y * X0 - d2x * Y0) * inv;

    double ZA = (A0 * Z0 + A1 * Z1 + A2 * Z2) * 0.5;
    double ZB = (B0 * Z0 + B1 * Z1 + B2 * Z2) * 0.5;
    double ZC = (C0 * Z0 + C1 * Z1 + C2 * Z2 + 1.0) * 0.5;

    double M0 = (fabs(A0) + fabs(B0)) * 135.0 + fabs(C0);
    double M1 = (fabs(A1) + fabs(B1)) * 135.0 + fabs(C1);
    double M2 = (fabs(A2) + fabs(B2)) * 135.0 + fabs(C2);
    float eps = (float)(1e-6 * fmax(M0, fmax(M1, M2)));

    float* rf = recf + (size_t)idx * 16;
    rf[0] = (float)A0; rf[1] = (float)B0; rf[2] = (float)C0;
    rf[3] = (float)A1; rf[4] = (float)B1; rf[5] = (float)C1;
    rf[6] = (float)A2; rf[7] = (float)B2; rf[8] = (float)C2;
    rf[9] = (float)ZA; rf[10] = (float)ZB; rf[11] = (float)ZC;
    rf[12] = (float)sg; rf[13] = eps; rf[14] = 0.f; rf[15] = 0.f;

    double* rd = recd + (size_t)idx * 10;
    rd[0] = A0; rd[1] = B0; rd[2] = C0;
    rd[3] = A1; rd[4] = B1; rd[5] = C1;
    rd[6] = A2; rd[7] = B2; rd[8] = C2; rd[9] = 0.0;

    float x0 = (float)X0, y0 = (float)Y0;
    float x1 = (float)X1, y1 = (float)Y1;
    float x2 = (float)X2, y2 = (float)Y2;
    float xmn = fminf(x0, fminf(x1, x2)) - 0.5f;
    float xmx = fmaxf(x0, fmaxf(x1, x2)) + 0.5f;
    float ymn = fminf(y0, fminf(y1, y2)) - 0.5f;
    float ymx = fmaxf(y0, fmaxf(y1, y2)) + 0.5f;
    int txmin = (int)ceilf((xmn - 7.f) * 0.125f);
    int txmax = (int)floorf(xmx * 0.125f);
    int tymin = (int)ceilf((ymn - 7.f) * 0.125f);
    int tymax = (int)floorf(ymx * 0.125f);
    txmin = max(0, min(15, txmin)); txmax = max(0, min(15, txmax));
    tymin = max(0, min(15, tymin)); tymax = max(0, min(15, tymax));
    bbox[idx] = (sg == 0.0) ? (1 | (0 << 8) | (1 << 16) | (0 << 24))
                            : (txmin | (txmax << 8) | (tymin << 16) | (tymax << 24));
}

// ---------------------------------------------------------------------------
// Per-survivor body (R7 Chebyshev numerics, verbatim). `live` is wave-uniform;
// false only for the dummy second face of an odd survivor count.
// ---------------------------------------------------------------------------
__device__ __forceinline__ void fof_body(const float* __restrict__ r,
                                         const double* __restrict__ rd,
                                         bool live, float px, float py,
                                         float& acc0, float& acc15, f2* accP) {
    float l0 = fmaf(r[0], py, fmaf(r[1], px, r[2]));
    float l1 = fmaf(r[3], py, fmaf(r[4], px, r[5]));
    float l2 = fmaf(r[6], py, fmaf(r[7], px, r[8]));
    float lmin = fminf(fminf(l0, l1), l2);
    float amin = fminf(fminf(__builtin_fabsf(l0), __builtin_fabsf(l1)),
                       __builtin_fabsf(l2));
    bool inside = lmin >= 0.f;
    if (__builtin_expect(live && __any(amin < r[13]), 0)) {  // rare exact path
        double pyd = (double)py, pxd = (double)px;
        double L0 = fma(rd[0], pyd, fma(rd[1], pxd, rd[2]));
        double L1 = fma(rd[3], pyd, fma(rd[4], pxd, rd[5]));
        double L2 = fma(rd[6], pyd, fma(rd[7], pxd, rd[8]));
        inside = (L0 >= 0.0) & (L1 >= 0.0) & (L2 >= 0.0);
    }
    float sg_eff = live ? r[12] : 0.f;
    float w = inside ? sg_eff : 0.f;

    if (__any(w != 0.f)) {
        float zt = fmaf(r[9], py, fmaf(r[10], px, r[11]));
        zt = fminf(fmaxf(zt, 0.f), 1.f);
        // HW trig in revolutions: sin(pi zt)=vsin(zt/2), sin(2pi zt)=vsin(zt),
        // cos(2pi zt)=vcos(zt); zt in [0,1] -> no argument reduction.
        float hz = 0.5f * zt;
        float s1, s2, c2;
        asm("v_sin_f32 %0, %1" : "=v"(s1) : "v"(hz));
        asm("v_sin_f32 %0, %1" : "=v"(s2) : "v"(zt));
        asm("v_cos_f32 %0, %1" : "=v"(c2) : "v"(zt));
        float twoc2 = c2 + c2;

        acc0 = fmaf(w, 1.f - zt, acc0);
        f2 w2;  w2.x = w;      w2.y = w;
        f2 t2;  t2.x = twoc2;  t2.y = twoc2;
        f2 um1; um1.x = -s1;   um1.y = 0.f;   // (s_{-1}, s_0)
        f2 u0;  u0.x = s1;     u0.y = s2;     // (s_1, s_2)
        accP[0] += w2 * u0;
        f2 u1 = t2 * u0 - um1;  accP[1] += w2 * u1;   // (s_3, s_4)
        f2 uu2 = t2 * u1 - u0;  accP[2] += w2 * uu2;  // (s_5, s_6)
        f2 u3 = t2 * uu2 - u1;  accP[3] += w2 * u3;   // (s_7, s_8)
        f2 u4 = t2 * u3 - uu2;  accP[4] += w2 * u4;   // (s_9, s_10)
        f2 u5 = t2 * u4 - u3;   accP[5] += w2 * u5;   // (s_11,s_12)
        f2 u6 = t2 * u5 - u4;   accP[6] += w2 * u6;   // (s_13,s_14)
        float s15 = fmaf(twoc2, u6.x, -u5.x);
        acc15 = fmaf(w, s15, acc15);
    }
}

// ---------------------------------------------------------------------------
// Kernel 2: main. 512 blocks (XOR-0x88 pairing, proven R7) x 1024 threads;
// 16 waves x 64 faces. R12 changes (R11 lesson: issue-bound, so cut
// iterations and issue, not latency):
//  1. Ballot-phase EDGE-CORNER reject: max of each edge function over the
//     tile rect is at a sign-picked corner; lmax_i < -eps for any edge =>
//     every pixel is >= eps outside => f64 path would also say outside =>
//     rejection is decision-equivalent. Cuts survivors ~32% -> ~21%.
//  2. 2-survivor unroll with unconditional record loads (both s_loads in
//     flight; independent bodies interleave; dummy face zeroed via `live`).
// ---------------------------------------------------------------------------
__global__ __launch_bounds__(1024) void fof_main(const float* __restrict__ recf,
                                                 const double* __restrict__ recd,
                                                 const int* __restrict__ bbox,
                                                 float* __restrict__ out) {
    __shared__ float S1[8][64][17];
    __shared__ float S2[4][64][17];
    __shared__ float S3[2][64][17];
    __shared__ float S4[64][17];

    int blk  = blockIdx.x;                 // 0..511
    int b    = blk & 1;
    int t0   = blk >> 1;                   // 0..255
    int tile = b ? (t0 ^ 0x88) : t0;       // heavy<->light pairing
    int ty   = tile >> 4;
    int tx   = tile & 15;
    int wv   = __builtin_amdgcn_readfirstlane((int)(threadIdx.x >> 6));  // 0..15
    int lane = threadIdx.x & 63;

    float px = (float)(tx * 8 + (lane & 7));
    float py = (float)(ty * 8 + (lane >> 3));

    float acc0 = 0.f, acc15 = 0.f;
    f2 accP[7];
#pragma unroll
    for (int j = 0; j < 7; ++j) { accP[j].x = 0.f; accP[j].y = 0.f; }

    int gfb = b * FF + wv * 64;            // this wave's 64-face chunk

    // ---- ballot phase: bbox + edge-corner reject (lane-parallel) ----
    int pk = bbox[gfb + lane];
    int txmin = pk & 255, txmax = (pk >> 8) & 255;
    int tymin = (pk >> 16) & 255, tymax = (pk >> 24) & 255;
    bool pass = !((tx < txmin) | (tx > txmax) | (ty < tymin) | (ty > tymax));

    {
        const float* rl = recf + (size_t)(gfb + lane) * 16;
        float4 q0 = *(const float4*)(rl);        // A0 B0 C0 A1
        float4 q1 = *(const float4*)(rl + 4);    // B1 C1 A2 B2
        float4 q2 = *(const float4*)(rl + 8);    // C2 ZA ZB ZC
        float4 q3 = *(const float4*)(rl + 12);   // sg eps - -
        float fx0 = (float)(tx * 8), fx1 = (float)(tx * 8 + 7);
        float fy0 = (float)(ty * 8), fy1 = (float)(ty * 8 + 7);
        float e0 = fmaf(q0.x, (q0.x >= 0.f ? fy1 : fy0),
                   fmaf(q0.y, (q0.y >= 0.f ? fx1 : fx0), q0.z));
        float e1 = fmaf(q0.w, (q0.w >= 0.f ? fy1 : fy0),
                   fmaf(q1.x, (q1.x >= 0.f ? fx1 : fx0), q1.y));
        float e2 = fmaf(q1.z, (q1.z >= 0.f ? fy1 : fy0),
                   fmaf(q1.w, (q1.w >= 0.f ? fx1 : fx0), q2.x));
        float eps = q3.y;
        pass = pass & (e0 >= -eps) & (e1 >= -eps) & (e2 >= -eps);
    }
    unsigned long long m = __ballot(pass);

    // ---- survivor loop, 2 faces per trip ----
    while (m) {
        int j0 = __builtin_amdgcn_readfirstlane(__builtin_ctzll(m));
        m &= m - 1;
        bool have2 = (m != 0ULL);
        unsigned long long ms = m | (unsigned long long)(m == 0ULL);
        int j1 = __builtin_amdgcn_readfirstlane(__builtin_ctzll(ms));
        m &= m - 1;                                  // 0 stays 0

        const float*  ra  = recf + (size_t)(gfb + j0) * 16;
        const double* rda = recd + (size_t)(gfb + j0) * 10;
        const float*  rb  = recf + (size_t)(gfb + j1) * 16;
        const double* rdb = recd + (size_t)(gfb + j1) * 10;

        fof_body(ra, rda, true,  px, py, acc0, acc15, accP);
        fof_body(rb, rdb, have2, px, py, acc0, acc15, accP);
    }

    float accv[16];
    accv[0] = acc0;
#pragma unroll
    for (int j = 0; j < 7; ++j) { accv[2 * j + 1] = accP[j].x; accv[2 * j + 2] = accP[j].y; }
    accv[15] = acc15;

    // 16 -> 8 -> 4 -> 2 -> 1 (disjoint stage buffers; write-sync-read)
    if (wv >= 8) {
#pragma unroll
        for (int k = 0; k < CC; ++k) S1[wv - 8][lane][k] = accv[k];
    }
    __syncthreads();
    if (wv < 8) {
#pragma unroll
        for (int k = 0; k < CC; ++k) accv[k] += S1[wv][lane][k];
    }
    if (wv >= 4 && wv < 8) {
#pragma unroll
        for (int k = 0; k < CC; ++k) S2[wv - 4][lane][k] = accv[k];
    }
    __syncthreads();
    if (wv < 4) {
#pragma unroll
        for (int k = 0; k < CC; ++k) accv[k] += S2[wv][lane][k];
    }
    if (wv == 2 || wv == 3) {
#pragma unroll
        for (int k = 0; k < CC; ++k) S3[wv - 2][lane][k] = accv[k];
    }
    __syncthreads();
    if (wv < 2) {
#pragma unroll
        for (int k = 0; k < CC; ++k) accv[k] += S3[wv][lane][k];
    }
    if (wv == 1) {
#pragma unroll
        for (int k = 0; k < CC; ++k) S4[lane][k] = accv[k];
    }
    __syncthreads();
    if (wv == 0) {
        int xo = tx * 8 + (lane & 7);
        int yo = ty * 8 + (lane >> 3);
#pragma unroll
        for (int k = 0; k < CC; ++k) {
            float val = accv[k] + S4[lane][k];
            float scale = (k == 0) ? 1.f : (-2.f / (PIF * (float)k));
            out[(((b * CC + k) * HH) + yo) * HH + xo] = val * scale;
        }
    }
}

extern "C" void kernel_launch(void* const* d_in, const int* in_sizes, int n_in,
                              void* d_out, int out_size, void* d_ws, size_t ws_size,
                              hipStream_t stream) {
    const float* v = (const float*)d_in[0];
    float* out = (float*)d_out;

    // ws: recf 2048*16*4 = 131072 B | recd 2048*10*8 = 163840 B | bbox 8192 B
    float*  recf = (float*)d_ws;
    double* recd = (double*)((char*)d_ws + 131072);
    int*    bbox = (int*)((char*)d_ws + 131072 + 163840);

    fof_setup<<<(BB * FF + 255) / 256, 256, 0, stream>>>(v, recf, recd, bbox);
    fof_main<<<BB * 256, 1024, 0, stream>>>(recf, recd, bbox, out);
}